// Round 3
// baseline (95.369 us; speedup 1.0000x reference)
//
#include <hip/hip_runtime.h>

#define BB 4096   // B
#define NN 8192   // N = 2B
#define DD 256    // D

// One wave (64 lanes) per row: float4 load -> 4 elems/lane, butterfly
// max+first-index reduce, lane0 writes row stats to workspace.
__global__ void rowmax_kernel(const float* __restrict__ out_a,
                              const float* __restrict__ out_b,
                              float* __restrict__ max_feat,
                              int* __restrict__ idx_max) {
    int gtid = blockIdx.x * blockDim.x + threadIdx.x;
    int row  = gtid >> 6;          // wave id
    int lane = threadIdx.x & 63;
    if (row >= NN) return;

    const float* rowp = (row < BB) ? (out_a + (size_t)row * DD)
                                   : (out_b + (size_t)(row - BB) * DD);
    float4 v = *reinterpret_cast<const float4*>(rowp + lane * 4);

    float best = v.x; int bi = lane * 4;
    if (v.y > best) { best = v.y; bi = lane * 4 + 1; }
    if (v.z > best) { best = v.z; bi = lane * 4 + 2; }
    if (v.w > best) { best = v.w; bi = lane * 4 + 3; }

    // 64-lane butterfly reduce; tie -> lower index (jnp.argmax = first max)
    #pragma unroll
    for (int off = 32; off >= 1; off >>= 1) {
        float ov = __shfl_xor(best, off, 64);
        int   oi = __shfl_xor(bi,   off, 64);
        if (ov > best || (ov == best && oi < bi)) { best = ov; bi = oi; }
    }

    if (lane == 0) {
        max_feat[row] = best;
        idx_max[row]  = bi;
    }
}

// Single block, 256 threads: LDS histogram + full loss reduction.
// Writes every element of d_out exactly once -> no pre-zero needed.
__global__ void __launch_bounds__(256)
finish_kernel(const float* __restrict__ out_a,
              const float* __restrict__ out_b,
              const int* __restrict__ neg_choice,
              const float* __restrict__ max_feat,
              const int* __restrict__ idx_max,
              float* __restrict__ out /* [0]=loss, [1..256]=num_max */) {
    __shared__ int   s_idx[NN];    // 32 KB
    __shared__ int   s_hist[DD];   // 1 KB
    __shared__ float s_part[4];

    int tid = threadIdx.x;

    // Load all argmax indices into LDS (coalesced)
    for (int i = tid; i < NN; i += 256) s_idx[i] = idx_max[i];
    s_hist[tid] = 0;
    __syncthreads();

    // Histogram via LDS atomics (~32 adds/bin)
    for (int i = tid; i < NN; i += 256) atomicAdd(&s_hist[s_idx[i]], 1);

    // Loss terms: 32 rows per thread, gathers are L2/L3-warm
    float acc = 0.0f;
    for (int i = tid; i < NN; i += 256) {
        int pair = (i < BB) ? (i + BB) : (i - BB);
        int e1   = (i < BB) ? i : (i - BB);
        int e2   = e1 + BB;
        int c = neg_choice[i];
        c += (c >= e1);
        c += (c >= e2);

        const float* rowp = (i < BB) ? (out_a + (size_t)i * DD)
                                     : (out_b + (size_t)(i - BB) * DD);
        float mf  = max_feat[i];
        float pos = mf - rowp[s_idx[pair]];
        float neg = mf - rowp[s_idx[c]];
        float md  = fmaxf(1.0f - neg, 0.0f);
        acc += pos + md * md;
    }

    __syncthreads();
    out[1 + tid] = (float)s_hist[tid];   // num_max, full overwrite

    // Block reduction of acc: wave butterfly -> LDS -> wave 0
    #pragma unroll
    for (int off = 32; off >= 1; off >>= 1)
        acc += __shfl_xor(acc, off, 64);
    if ((tid & 63) == 0) s_part[tid >> 6] = acc;
    __syncthreads();
    if (tid == 0)
        out[0] = 0.5f * (s_part[0] + s_part[1] + s_part[2] + s_part[3]);
}

extern "C" void kernel_launch(void* const* d_in, const int* in_sizes, int n_in,
                              void* d_out, int out_size, void* d_ws, size_t ws_size,
                              hipStream_t stream) {
    const float* out_a      = (const float*)d_in[0];
    const float* out_b      = (const float*)d_in[1];
    const int*   neg_choice = (const int*)d_in[2];
    float* out = (float*)d_out;

    float* max_feat = (float*)d_ws;
    int*   idx_max  = (int*)((char*)d_ws + NN * sizeof(float));

    // 8192 waves, 4 per 256-thread block -> 2048 blocks
    rowmax_kernel<<<NN / 4, 256, 0, stream>>>(out_a, out_b, max_feat, idx_max);

    finish_kernel<<<1, 256, 0, stream>>>(out_a, out_b, neg_choice,
                                         max_feat, idx_max, out);
}

// Round 4
// 71.087 us; speedup vs baseline: 1.3416x; 1.3416x over previous
//
#include <hip/hip_runtime.h>

#define BB 4096   // B
#define NN 8192   // N = 2B
#define DD 256    // D

// One wave (64 lanes) per row: float4 load -> 4 elems/lane, butterfly
// max+first-index reduce, lane0 writes row stats to workspace.
__global__ void rowmax_kernel(const float* __restrict__ out_a,
                              const float* __restrict__ out_b,
                              float* __restrict__ max_feat,
                              int* __restrict__ idx_max) {
    int gtid = blockIdx.x * blockDim.x + threadIdx.x;
    int row  = gtid >> 6;          // wave id
    int lane = threadIdx.x & 63;
    if (row >= NN) return;

    const float* rowp = (row < BB) ? (out_a + (size_t)row * DD)
                                   : (out_b + (size_t)(row - BB) * DD);
    float4 v = *reinterpret_cast<const float4*>(rowp + lane * 4);

    float best = v.x; int bi = lane * 4;
    if (v.y > best) { best = v.y; bi = lane * 4 + 1; }
    if (v.z > best) { best = v.z; bi = lane * 4 + 2; }
    if (v.w > best) { best = v.w; bi = lane * 4 + 3; }

    // 64-lane butterfly reduce; tie -> lower index (jnp.argmax = first max)
    #pragma unroll
    for (int off = 32; off >= 1; off >>= 1) {
        float ov = __shfl_xor(best, off, 64);
        int   oi = __shfl_xor(bi,   off, 64);
        if (ov > best || (ov == best && oi < bi)) { best = ov; bi = oi; }
    }

    if (lane == 0) {
        max_feat[row] = best;
        idx_max[row]  = bi;
    }
}

// 32 blocks x 256 threads: one row per thread. Per-block LDS histogram of
// this block's argmax bins (-> <=256 global adds/block, zero-bins skipped),
// loss term per row, block-reduced to 1 global atomic per block.
__global__ void __launch_bounds__(256)
loss_kernel(const float* __restrict__ out_a,
            const float* __restrict__ out_b,
            const int* __restrict__ neg_choice,
            const float* __restrict__ max_feat,
            const int* __restrict__ idx_max,
            float* __restrict__ out /* [0]=loss, [1..256]=num_max, pre-zeroed */) {
    __shared__ int   s_hist[DD];
    __shared__ float s_part[4];

    int tid = threadIdx.x;
    int r   = blockIdx.x * 256 + tid;

    s_hist[tid] = 0;
    __syncthreads();

    int my_bin = idx_max[r];
    atomicAdd(&s_hist[my_bin], 1);

    // Loss term
    int pair = (r < BB) ? (r + BB) : (r - BB);
    int e1   = (r < BB) ? r : (r - BB);
    int e2   = e1 + BB;
    int c = neg_choice[r];
    c += (c >= e1);
    c += (c >= e2);

    const float* rowp = (r < BB) ? (out_a + (size_t)r * DD)
                                 : (out_b + (size_t)(r - BB) * DD);
    float mf  = max_feat[r];
    float pos = mf - rowp[idx_max[pair]];
    float neg = mf - rowp[idx_max[c]];
    float md  = fmaxf(1.0f - neg, 0.0f);
    float acc = pos + md * md;

    // Block reduction: wave butterfly -> LDS -> wave 0 -> 1 atomic
    #pragma unroll
    for (int off = 32; off >= 1; off >>= 1)
        acc += __shfl_xor(acc, off, 64);
    if ((tid & 63) == 0) s_part[tid >> 6] = acc;
    __syncthreads();

    if (tid == 0)
        atomicAdd(&out[0], 0.5f * (s_part[0] + s_part[1] + s_part[2] + s_part[3]));

    // Histogram flush (skip empty bins)
    int h = s_hist[tid];
    if (h != 0) atomicAdd(&out[1 + tid], (float)h);
}

extern "C" void kernel_launch(void* const* d_in, const int* in_sizes, int n_in,
                              void* d_out, int out_size, void* d_ws, size_t ws_size,
                              hipStream_t stream) {
    const float* out_a      = (const float*)d_in[0];
    const float* out_b      = (const float*)d_in[1];
    const int*   neg_choice = (const int*)d_in[2];
    float* out = (float*)d_out;           // [0]=loss, [1..256]=num_max

    float* max_feat = (float*)d_ws;
    int*   idx_max  = (int*)((char*)d_ws + NN * sizeof(float));

    // d_out is poisoned before every replay; zero the 257 floats we accumulate.
    hipMemsetAsync(d_out, 0, (size_t)out_size * sizeof(float), stream);

    // 8192 waves, 4 per 256-thread block -> 2048 blocks
    rowmax_kernel<<<NN / 4, 256, 0, stream>>>(out_a, out_b, max_feat, idx_max);

    // 8192 rows, 1 thread each -> 32 blocks
    loss_kernel<<<NN / 256, 256, 0, stream>>>(out_a, out_b, neg_choice,
                                              max_feat, idx_max, out);
}

// Round 8
// 66.729 us; speedup vs baseline: 1.4292x; 1.0653x over previous
//
#include <hip/hip_runtime.h>

#define BB 4096   // B
#define NN 8192   // N = 2B
#define DD 256    // D

// One wave (64 lanes) per row: float4 load -> 4 elems/lane, butterfly
// max+first-index reduce, lane0 writes row stats to workspace.
// Block 0 additionally zeroes the 257-float output (d_out is 0xAA-poisoned
// before every replay); the kernel boundary orders these zeros before
// loss_kernel's atomics.
__global__ void rowmax_kernel(const float* __restrict__ out_a,
                              const float* __restrict__ out_b,
                              float* __restrict__ max_feat,
                              int* __restrict__ idx_max,
                              float* __restrict__ out /* 257 floats */) {
    int tid  = threadIdx.x;
    int gtid = blockIdx.x * blockDim.x + tid;
    int row  = gtid >> 6;          // wave id
    int lane = tid & 63;

    if (blockIdx.x == 0) {
        out[tid] = 0.0f;
        if (tid == 0) out[256] = 0.0f;
    }
    if (row >= NN) return;

    const float* rowp = (row < BB) ? (out_a + (size_t)row * DD)
                                   : (out_b + (size_t)(row - BB) * DD);
    float4 v = *reinterpret_cast<const float4*>(rowp + lane * 4);

    float best = v.x; int bi = lane * 4;
    if (v.y > best) { best = v.y; bi = lane * 4 + 1; }
    if (v.z > best) { best = v.z; bi = lane * 4 + 2; }
    if (v.w > best) { best = v.w; bi = lane * 4 + 3; }

    // 64-lane butterfly reduce; tie -> lower index (jnp.argmax = first max)
    #pragma unroll
    for (int off = 32; off >= 1; off >>= 1) {
        float ov = __shfl_xor(best, off, 64);
        int   oi = __shfl_xor(bi,   off, 64);
        if (ov > best || (ov == best && oi < bi)) { best = ov; bi = oi; }
    }

    if (lane == 0) {
        max_feat[row] = best;
        idx_max[row]  = bi;
    }
}

// 32 blocks x 256 threads: one row per thread. Per-block LDS histogram of
// this block's argmax bins (-> <=256 global adds/block, zero-bins skipped),
// loss term per row, block-reduced to 1 global atomic per block.
__global__ void __launch_bounds__(256)
loss_kernel(const float* __restrict__ out_a,
            const float* __restrict__ out_b,
            const int* __restrict__ neg_choice,
            const float* __restrict__ max_feat,
            const int* __restrict__ idx_max,
            float* __restrict__ out /* [0]=loss, [1..256]=num_max, pre-zeroed */) {
    __shared__ int   s_hist[DD];
    __shared__ float s_part[4];

    int tid = threadIdx.x;
    int r   = blockIdx.x * 256 + tid;

    s_hist[tid] = 0;
    __syncthreads();

    int my_bin = idx_max[r];
    atomicAdd(&s_hist[my_bin], 1);

    // Loss term
    int pair = (r < BB) ? (r + BB) : (r - BB);
    int e1   = (r < BB) ? r : (r - BB);
    int e2   = e1 + BB;
    int c = neg_choice[r];
    c += (c >= e1);
    c += (c >= e2);

    const float* rowp = (r < BB) ? (out_a + (size_t)r * DD)
                                 : (out_b + (size_t)(r - BB) * DD);
    float mf  = max_feat[r];
    float pos = mf - rowp[idx_max[pair]];
    float neg = mf - rowp[idx_max[c]];
    float md  = fmaxf(1.0f - neg, 0.0f);
    float acc = pos + md * md;

    // Block reduction: wave butterfly -> LDS -> wave 0 -> 1 atomic
    #pragma unroll
    for (int off = 32; off >= 1; off >>= 1)
        acc += __shfl_xor(acc, off, 64);
    if ((tid & 63) == 0) s_part[tid >> 6] = acc;
    __syncthreads();

    if (tid == 0)
        atomicAdd(&out[0], 0.5f * (s_part[0] + s_part[1] + s_part[2] + s_part[3]));

    // Histogram flush (skip empty bins)
    int h = s_hist[tid];
    if (h != 0) atomicAdd(&out[1 + tid], (float)h);
}

extern "C" void kernel_launch(void* const* d_in, const int* in_sizes, int n_in,
                              void* d_out, int out_size, void* d_ws, size_t ws_size,
                              hipStream_t stream) {
    const float* out_a      = (const float*)d_in[0];
    const float* out_b      = (const float*)d_in[1];
    const int*   neg_choice = (const int*)d_in[2];
    float* out = (float*)d_out;           // [0]=loss, [1..256]=num_max

    float* max_feat = (float*)d_ws;
    int*   idx_max  = (int*)((char*)d_ws + NN * sizeof(float));

    // 8192 waves, 4 per 256-thread block -> 2048 blocks (block 0 zeros d_out)
    rowmax_kernel<<<NN / 4, 256, 0, stream>>>(out_a, out_b, max_feat, idx_max, out);

    // 8192 rows, 1 thread each -> 32 blocks
    loss_kernel<<<NN / 256, 256, 0, stream>>>(out_a, out_b, neg_choice,
                                              max_feat, idx_max, out);
}